// Round 6
// baseline (309.680 us; speedup 1.0000x reference)
//
#include <hip/hip_runtime.h>
#include <stdint.h>

// Problem constants (fixed by the reference)
#define E_EXPERTS 8
#define D_DIM 1024
#define I_DIM 2048
#define T_TOKENS 4096
#define NSLOTS 8192                 // T * K
#define TILE 128
#define MAXPAD (NSLOTS + E_EXPERTS * TILE)   // 9216
#define TPX 9                       // tiles per XCD chunk (8*9=72 >= max 71 tiles)

#define XCVT_BLOCKS 2048
#define WPACK_BLOCKS 2048           // per weight matrix
// prep: routing + x-cvt + w1-pack ONLY (w2-pack moved into gemm1 dispatch)
#define PREP_GRID (1 + XCVT_BLOCKS + WPACK_BLOCKS)
#define G1_GEMM_BLOCKS (8 * TPX * (I_DIM / 128))            // 1152
#define G1_GRID (WPACK_BLOCKS + G1_GEMM_BLOCKS)             // 2048 + 1152

typedef __attribute__((ext_vector_type(8))) short bf16x8;
typedef __attribute__((ext_vector_type(4))) float f32x4;

__device__ __forceinline__ unsigned short f2b(float f) {
  union { float f; uint32_t u; } v; v.f = f;
  uint32_t r = v.u + 0x7FFFu + ((v.u >> 16) & 1u);   // round-to-nearest-even
  return (unsigned short)(r >> 16);
}
__device__ __forceinline__ float b2f(unsigned short u) {
  union { uint32_t u; float f; } v; v.u = ((uint32_t)u) << 16; return v.f;
}

// async 16B global -> LDS (dest = wave-uniform base + lane*16)
__device__ __forceinline__ void async16(const unsigned short* g, unsigned short* l) {
  __builtin_amdgcn_global_load_lds(
      (const __attribute__((address_space(1))) void*)g,
      (__attribute__((address_space(3))) void*)l, 16, 0, 0);
}

// ---------------- weight packing body ----------------
// Packed-tile layout: for (e, nt, kt) the 16KB block holds, at chunk position
// (rr*8 + cc8), the source k-chunk (cc8 ^ (rr&7)) of n-row rr:
//   elem (rr*8 + cc8)*8 + t  =  w[e][kt*64 + (cc8^(rr&7))*8 + t][nt*128 + rr]
// One contiguous 16KB write region per block. LDS 64x129 fp32 transpose tile;
// loader map row=i*8+(tid&7), c4=(tid>>3)*4 -> write banks 2-way (free, m136);
// read banks (c*8+t+rr)%32 2-way (free).
__device__ __forceinline__ void wpack_body(
    int mat, int sub, float* ts, int tid,
    const float* __restrict__ w1, const float* __restrict__ w2,
    unsigned short* __restrict__ w1t, unsigned short* __restrict__ w2t) {
  int e = sub >> 8, rem = sub & 255;
  const float* src; unsigned short* dst; int C, k0, n0;
  if (mat == 0) {                    // w1 [D=K=1024][I=N=2048]: 16 nt x 16 kt
    int nt = rem >> 4, kt = rem & 15;
    C = I_DIM; k0 = kt * 64; n0 = nt * 128;
    src = w1 + (size_t)e * D_DIM * I_DIM;
    dst = w1t + ((size_t)((e * 16 + nt) * 16 + kt)) * 8192;
  } else {                           // w2 [I=K=2048][D=N=1024]: 8 nt x 32 kt
    int nt = rem >> 5, kt = rem & 31;
    C = D_DIM; k0 = kt * 64; n0 = nt * 128;
    src = w2 + (size_t)e * D_DIM * I_DIM;
    dst = w2t + ((size_t)((e * 8 + nt) * 32 + kt)) * 8192;
  }
  int lrow = tid & 7, c4 = (tid >> 3) * 4;
#pragma unroll
  for (int i = 0; i < 8; i++) {
    int row = i * 8 + lrow;
    float4 v = *(const float4*)(src + (size_t)(k0 + row) * C + n0 + c4);
    float* d = ts + row * 129 + c4;
    d[0] = v.x; d[1] = v.y; d[2] = v.z; d[3] = v.w;
  }
  __syncthreads();
#pragma unroll
  for (int j = 0; j < 4; j++) {
    int q = j * 256 + tid;
    int rr = q >> 3, cc8 = q & 7;
    int c = cc8 ^ (rr & 7);
    bf16x8 o;
#pragma unroll
    for (int t = 0; t < 8; t++)
      o[t] = (short)f2b(ts[(c * 8 + t) * 129 + rr]);
    *(bf16x8*)(dst + (size_t)q * 8) = o;
  }
}

// ---------------- GEMM body ----------------
// 128x128 tile, BK=64, bf16 MFMA 16x16x32, global_load_lds width-16 staging.
// B from packed tiles (linear 16KB copy per kt). MFMA operands swapped
// (bfr, af) -> transposed D: lane holds 4 consecutive N-cols -> ushort4 stores.
// PHASE 1: A = xb gathered via tok[slot]; silu -> Hout bf16 [slot][NDIM]
// PHASE 2: A = hbuf rows by slot, split-K=2; raw bf16 -> Yout[kh][slot][NDIM]
template <int KLEN, int KFULL, int NDIM, int PHASE>
__device__ __forceinline__ void moe_gemm_body(
    int id, unsigned short* As, unsigned short* Bs,
    const unsigned short* __restrict__ Amat, const unsigned short* __restrict__ Bt,
    const int* __restrict__ desc, const int* __restrict__ ntiles_p,
    const int* __restrict__ tok, unsigned short* __restrict__ Hout) {
  int xcd = id & 7, r = id >> 3;
  int ti = xcd * TPX + r % TPX;
  int q = r / TPX;
  int nb, kh;
  if (PHASE == 1) { nb = q; kh = 0; }
  else           { kh = q & 1; nb = q >> 1; }
  if (ti >= *ntiles_p) return;
  int e = desc[2 * ti];
  int slot0 = desc[2 * ti + 1];

  int tid = threadIdx.x;
  int lane = tid & 63;
  int wave = tid >> 6;
  int wm = (wave >> 1) * 64, wn = (wave & 1) * 64;
  int l15 = lane & 15, quad = lane >> 4;

  f32x4 acc[4][4] = {};

  int sr = tid >> 3;                               // row base, 0..31
  int ldoff = (((lane & 7) ^ (lane >> 3)) * 8);    // content-chunk offset (swizzle inverse)

  const unsigned short* arow[4];
#pragma unroll
  for (int p = 0; p < 4; p++) {
    int rr = sr + p * 32;
    int row = (PHASE == 1) ? tok[slot0 + rr] : (slot0 + rr);
    arow[p] = Amat + (size_t)row * KFULL + kh * KLEN + ldoff;
  }
  const unsigned short* Bpack =
      Bt + ((((size_t)e * (NDIM / 128) + nb) * (KFULL / 64) + (size_t)kh * (KLEN / 64)) << 13) +
      (size_t)tid * 8;

  for (int kt = 0; kt < KLEN / 64; kt++) {
    int k0 = kt * 64;
#pragma unroll
    for (int p = 0; p < 4; p++) {
      unsigned short* adst = As + (size_t)(p * 256 + wave * 64) * 8;
      unsigned short* bdst = Bs + (size_t)(p * 256 + wave * 64) * 8;
      async16(arow[p] + k0, adst);
      async16(Bpack + (size_t)kt * 8192 + p * 2048, bdst);
    }
    __syncthreads();
#pragma unroll
    for (int ks = 0; ks < 2; ks++) {
      bf16x8 af[4], bfr[4];
#pragma unroll
      for (int i = 0; i < 4; i++) {
        int rr = wm + i * 16 + l15;
        int cc = (((ks * 4 + quad) ^ (rr & 7)) * 8);
        af[i] = *(const bf16x8*)&As[rr * 64 + cc];
      }
#pragma unroll
      for (int j = 0; j < 4; j++) {
        int rr = wn + j * 16 + l15;
        int cc = (((ks * 4 + quad) ^ (rr & 7)) * 8);
        bfr[j] = *(const bf16x8*)&Bs[rr * 64 + cc];
      }
#pragma unroll
      for (int i = 0; i < 4; i++)
#pragma unroll
        for (int j = 0; j < 4; j++)
          acc[i][j] = __builtin_amdgcn_mfma_f32_16x16x32_bf16(bfr[j], af[i], acc[i][j], 0, 0, 0);
    }
    __syncthreads();
  }

  // Epilogue (transposed D): slot = slot0+wm+i*16+l15; cols quad*4+rg.
#pragma unroll
  for (int i = 0; i < 4; i++) {
    int slotr = slot0 + wm + i * 16 + l15;
    size_t base = (PHASE == 1) ? (size_t)slotr * NDIM
                               : ((size_t)kh * MAXPAD + slotr) * NDIM;
#pragma unroll
    for (int j = 0; j < 4; j++) {
      int colbase = nb * 128 + wn + j * 16 + quad * 4;
      ushort4 o;
#pragma unroll
      for (int rg = 0; rg < 4; rg++) {
        float v = acc[i][j][rg];
        if (PHASE == 1) v = v / (1.f + __expf(-v));        // silu
        ((unsigned short*)&o)[rg] = f2b(v);
      }
      *(ushort4*)(Hout + base + colbase) = o;
    }
  }
}

// ---------------- prep: routing + x-cvt + w1-pack ----------------
__global__ __launch_bounds__(256) void prep_k(
    const float* __restrict__ x, const float* __restrict__ w1, const float* __restrict__ w2,
    const int* __restrict__ se,
    unsigned short* __restrict__ xb, unsigned short* __restrict__ w1t,
    unsigned short* __restrict__ w2t,
    int* __restrict__ ntiles, int* __restrict__ desc,
    int* __restrict__ tok, int* __restrict__ slot_of) {
  int b = blockIdx.x;
  int tid = threadIdx.x;

  if (b == 0) {
    // ---- single-workgroup routing ----
    __shared__ int scnt[E_EXPERTS], sbase[E_EXPERTS + 1], scur[E_EXPERTS];
    if (tid < E_EXPERTS) scnt[tid] = 0;
    __syncthreads();
    for (int s = tid; s < NSLOTS; s += 256) atomicAdd(&scnt[se[s]], 1);
    __syncthreads();
    if (tid == 0) {
      int acc = 0, nt = 0;
      for (int e = 0; e < E_EXPERTS; e++) {
        int n = scnt[e];
        sbase[e] = acc;
        scur[e] = acc;
        int pad = (n + TILE - 1) & ~(TILE - 1);
        for (int m = 0; m * TILE < pad; m++) { desc[2 * nt] = e; desc[2 * nt + 1] = acc + m * TILE; nt++; }
        acc += pad;
      }
      sbase[E_EXPERTS] = acc;
      *ntiles = nt;
    }
    __syncthreads();
    // pad slots -> token 0 (weight is never read for pads; rows are discarded)
    for (int e = 0; e < E_EXPERTS; e++) {
      int s0 = sbase[e] + scnt[e], s1 = sbase[e + 1];
      for (int s = s0 + tid; s < s1; s += 256) tok[s] = 0;
    }
    // scatter (disjoint from pad range)
    for (int s = tid; s < NSLOTS; s += 256) {
      int e = se[s];
      int pos = atomicAdd(&scur[e], 1);
      tok[pos] = s >> 1;      // K=2
      slot_of[s] = pos;
    }
    return;
  }

  int bb = b - 1;

  if (bb < XCVT_BLOCKS) {
    // ---- x fp32 -> bf16, 8 elems/thread ----
    size_t i = ((size_t)bb * 256 + tid) * 8;
    float4 v0 = *(const float4*)(x + i);
    float4 v1 = *(const float4*)(x + i + 4);
    ushort4 o0, o1;
    o0.x = f2b(v0.x); o0.y = f2b(v0.y); o0.z = f2b(v0.z); o0.w = f2b(v0.w);
    o1.x = f2b(v1.x); o1.y = f2b(v1.y); o1.z = f2b(v1.z); o1.w = f2b(v1.w);
    *(ushort4*)(xb + i) = o0;
    *(ushort4*)(xb + i + 4) = o1;
    return;
  }

  // ---- w1 pack ----
  __shared__ float ts[64 * 129];
  wpack_body(0, bb - XCVT_BLOCKS, ts, tid, w1, w2, w1t, w2t);
}

// ---------------- fused: w2-pack (blocks [0,2048)) + gemm phase 1 ----------------
// The two halves touch disjoint buffers (pack: w2->w2t; gemm: xb,w1t->hbuf)
// and have NO ordering dependency -> safe in one dispatch, overlapping the
// memory-bound pack stream under the compute-bound GEMM (gemm1 alone used
// only ~473 GB/s of the ~6.3 TB/s achievable).
__global__ __launch_bounds__(256) void g1_fused_k(
    const float* __restrict__ w1, const float* __restrict__ w2,
    unsigned short* __restrict__ w1t, unsigned short* __restrict__ w2t,
    const unsigned short* __restrict__ xb,
    const int* __restrict__ desc, const int* __restrict__ ntiles_p,
    const int* __restrict__ tok, unsigned short* __restrict__ hbuf) {
  __shared__ __align__(16) char smem[64 * 129 * 4];   // 33024B, covers both uses
  int b = blockIdx.x;
  int tid = threadIdx.x;
  if (b < WPACK_BLOCKS) {
    wpack_body(1, b, (float*)smem, tid, w1, w2, w1t, w2t);
    return;
  }
  unsigned short* As = (unsigned short*)smem;
  unsigned short* Bs = As + 8192;
  moe_gemm_body<1024, 1024, I_DIM, 1>(b - WPACK_BLOCKS, As, Bs,
                                      xb, w1t, desc, ntiles_p, tok, hbuf);
}

// ---------------- gemm phase 2 ----------------
__global__ __launch_bounds__(256) void gemm2_k(
    const unsigned short* __restrict__ Amat, const unsigned short* __restrict__ Bt,
    const int* __restrict__ desc, const int* __restrict__ ntiles_p,
    const int* __restrict__ tok, unsigned short* __restrict__ Hout) {
  __shared__ unsigned short As[128 * 64];
  __shared__ unsigned short Bs[128 * 64];
  moe_gemm_body<1024, 2048, D_DIM, 2>(blockIdx.x, As, Bs,
                                      Amat, Bt, desc, ntiles_p, tok, Hout);
}

// out[t][d] = sum_k rw[t*2+k] * (y0[slot_of[t*2+k]][d] + y1[slot_of[t*2+k]][d])
__global__ void combine_k(const unsigned short* __restrict__ y, const float* __restrict__ rw,
                          const int* __restrict__ slot_of, float* __restrict__ out) {
  int g = blockIdx.x * blockDim.x + threadIdx.x;   // T*128 threads, 8 elems each
  int t = g >> 7, dd = (g & 127) * 8;
  int s0 = slot_of[2 * t], s1 = slot_of[2 * t + 1];
  float w0 = rw[2 * t], w1 = rw[2 * t + 1];
  bf16x8 a = *(const bf16x8*)(y + (size_t)s0 * D_DIM + dd);
  bf16x8 bq = *(const bf16x8*)(y + ((size_t)MAXPAD + s0) * D_DIM + dd);
  bf16x8 c = *(const bf16x8*)(y + (size_t)s1 * D_DIM + dd);
  bf16x8 d = *(const bf16x8*)(y + ((size_t)MAXPAD + s1) * D_DIM + dd);
  float4 o0, o1;
#pragma unroll
  for (int k = 0; k < 8; k++) {
    float v = w0 * (b2f((unsigned short)a[k]) + b2f((unsigned short)bq[k])) +
              w1 * (b2f((unsigned short)c[k]) + b2f((unsigned short)d[k]));
    if (k < 4) ((float*)&o0)[k] = v; else ((float*)&o1)[k - 4] = v;
  }
  float* op = out + (size_t)t * D_DIM + dd;
  *(float4*)op = o0;
  *(float4*)(op + 4) = o1;
}

extern "C" void kernel_launch(void* const* d_in, const int* in_sizes, int n_in,
                              void* d_out, int out_size, void* d_ws, size_t ws_size,
                              hipStream_t stream) {
  (void)in_sizes; (void)n_in; (void)ws_size; (void)out_size;
  const float* x  = (const float*)d_in[0];
  const float* rw = (const float*)d_in[1];
  const int*   se = (const int*)d_in[2];
  const float* w1 = (const float*)d_in[3];
  const float* w2 = (const float*)d_in[4];
  float* out = (float*)d_out;
  char* ws = (char*)d_ws;

  int* ntiles  = (int*)(ws + 128);
  int* desc    = (int*)(ws + 256);
  int* tok     = (int*)(ws + 4096);          // MAXPAD ints -> ends 40960
  int* slot_of = (int*)(ws + 40960);         // NSLOTS ints -> ends 73728
  unsigned short* xb   = (unsigned short*)(ws + 131072);              // 8.39 MB
  unsigned short* w1t  = xb + (size_t)T_TOKENS * D_DIM;               // 33.55 MB (packed tiles)
  unsigned short* w2t  = w1t + (size_t)E_EXPERTS * D_DIM * I_DIM;     // 33.55 MB (packed tiles)
  unsigned short* hbuf = w2t + (size_t)E_EXPERTS * D_DIM * I_DIM;     // 37.75 MB
  // ypart overlays xb+w1t (both dead after phase 1): 37.75 MB <= 41.94 MB
  unsigned short* ypart = xb;

  // routing + x-cvt + w1-pack
  prep_k<<<PREP_GRID, 256, 0, stream>>>(x, w1, w2, se, xb, w1t, w2t,
                                        ntiles, desc, tok, slot_of);
  // w2-pack (independent) overlapped with phase-1 GEMM in one dispatch
  g1_fused_k<<<G1_GRID, 256, 0, stream>>>(w1, w2, w1t, w2t,
                                          xb, desc, ntiles, tok, hbuf);
  // Phase 2: [slots x 2048] @ w2t(packed) -> ypart, split-K=2;  grid 1152
  gemm2_k<<<8 * TPX * (D_DIM / 128) * 2, 256, 0, stream>>>(
      hbuf, w2t, desc, ntiles, tok, ypart);

  combine_k<<<T_TOKENS * 128 / 256, 256, 0, stream>>>(ypart, rw, slot_of, out);
}